// Round 7
// baseline (648.615 us; speedup 1.0000x reference)
//
#include <hip/hip_runtime.h>
#include <hip/hip_bf16.h>
#include <stdint.h>

typedef __attribute__((ext_vector_type(8))) short bf16x8;
typedef __attribute__((ext_vector_type(4))) short bf16x4;
typedef __attribute__((ext_vector_type(8))) unsigned short u16x8;
typedef __attribute__((ext_vector_type(4))) float f32x4;

#define B_SZ 2048
#define L_SZ 200
#define NROWS (B_SZ * L_SZ)   // 409600 valid rows
#define NT_PER_B 13           // 16-row tiles per batch (last ragged)

__device__ __forceinline__ short f2bf(float f) {
    __bf16 h = (__bf16)f;
    return __builtin_bit_cast(short, h);
}
__device__ __forceinline__ float bf2f(short s) {
    union { uint32_t u; float f; } v; v.u = ((uint32_t)(uint16_t)s) << 16;
    return v.f;
}
__device__ __forceinline__ float sigm(float x) {
    return 1.0f / (1.0f + __expf(-x));
}
// channel c = ct*16 + g*4 + j  <->  blob slot kap = (ct>>1)*32 + g*8 + (ct&1)*4 + j
__device__ __forceinline__ int chan_to_slot(int c) {
    return (c & 96) | (((c >> 2) & 3) << 3) | (((c >> 4) & 1) << 2) | (c & 3);
}

// ---------------- K0: weight prep + stat zeroing ----------------
// Aprime = W1a + W1c (f32 128x128 natural)
// Wf: bf16 A-frag blob of stacked [B'=W1b-W1c ; D=W1d] (256 kdims x 128 ch):
//   f = ((ct*8+kt)*64 + l)*8 + jj -> Wfeat[kdim = kt*32+(l>>4)*8+jj][ch = ct*16+(l&15)]
// W2fT: bf16 A-frag blob of W2^T, rows in slot order (as R6, proven)
// alpha1p[kap] = alpha1[c]
__global__ void k0_prep(const float* __restrict__ W1, const float* __restrict__ W2,
                        const float* __restrict__ alpha1,
                        float* __restrict__ Aprime, ushort* __restrict__ Wf,
                        ushort* __restrict__ W2fT, float* __restrict__ alpha1p,
                        float* __restrict__ stats)
{
    const int total = 16384 + 32768 + 4096 + 128 + 512;   // 53888
    for (int i = blockIdx.x * blockDim.x + threadIdx.x; i < total; i += gridDim.x * blockDim.x) {
        if (i < 16384) {
            int r = i >> 7, c = i & 127;
            Aprime[i] = W1[r * 128 + c] + W1[(256 + r) * 128 + c];
        } else if (i < 49152) {
            int f = i - 16384;
            int jj = f & 7, l = (f >> 3) & 63, kt = (f >> 9) & 7, ct = f >> 12;
            int kdim = kt * 32 + ((l >> 4) << 3) + jj;
            int ch = (ct << 4) + (l & 15);
            float v = (kdim < 128)
                ? (W1[(128 + kdim) * 128 + ch] - W1[(256 + kdim) * 128 + ch])
                : W1[(256 + kdim) * 128 + ch];   // 384 + (kdim-128)
            Wf[f] = (ushort)f2bf(v);
        } else if (i < 49152 + 4096) {
            int f = i - 49152;
            int jj = f & 7, l = (f >> 3) & 63, kt = (f >> 9) & 3, mt2 = f >> 11;
            int g = l >> 4;
            int c = kt * 32 + ((jj >> 2) << 4) + (g << 2) + (jj & 3);  // c(kap)
            int col = (mt2 << 4) + (l & 15);
            W2fT[f] = (ushort)f2bf(W2[c * 32 + col]);
        } else if (i < 49152 + 4096 + 128) {
            int c = i - (49152 + 4096);
            alpha1p[chan_to_slot(c)] = alpha1[c];
        } else {
            stats[i - (49152 + 4096 + 128)] = 0.0f;  // 512 f32: stats1(256)+stats2(64)+pad
        }
    }
}

// ---------------- K1: qA[b][c] = q[b]@A' + b1 ----------------
__global__ void k1_qA(const float* __restrict__ q, const float* __restrict__ Aprime,
                      const float* __restrict__ b1, float* __restrict__ qA)
{
    __shared__ float qs[128];
    int b = blockIdx.x, c = threadIdx.x;
    qs[c] = q[b * 128 + c];
    __syncthreads();
    float acc = b1[c];
    #pragma unroll 8
    for (int r = 0; r < 128; ++r) acc += qs[r] * Aprime[r * 128 + c];
    qA[b * 128 + c] = acc;
}

// ---------------- K2: pure streaming GEMM1, weights in LDS ----------------
// wave = one batch; 13 tiles of 16 rows. afr: k (kt 0..3) + q*k (kt 4..7).
// Swapped MFMA: acc[ct][j] = z1[row=r15][ch=ct*16+g*4+j]. Blob store 4x16B/lane.
// Invalid rows (>=200) stored as 0 (so S1 needs no mask).
__global__ void __launch_bounds__(256, 2) k2_main(
    const float* __restrict__ query, const float* __restrict__ keys,
    const float* __restrict__ qA, const ushort* __restrict__ Wf,
    ushort* __restrict__ z1b)
{
    __shared__ ushort wlds[32768];   // 64 KB weight frag blob
    const int tid = threadIdx.x;
    for (int i = tid; i < 4096; i += 256)
        ((u16x8*)wlds)[i] = ((const u16x8*)Wf)[i];
    __syncthreads();

    const int lane = tid & 63, wid = tid >> 6;
    const int b = blockIdx.x * 4 + wid;
    const int r15 = lane & 15, g = lane >> 4;

    const float* kbase = keys + (size_t)b * L_SZ * 128;

    // persistent q fragments + qA (per batch)
    f32x4 qv[4][2];
    #pragma unroll
    for (int kt = 0; kt < 4; ++kt) {
        const float* qp = query + (size_t)b * 128 + kt * 32 + g * 8;
        qv[kt][0] = *(const f32x4*)(qp);
        qv[kt][1] = *(const f32x4*)(qp + 4);
    }
    f32x4 qa[8];
    #pragma unroll
    for (int ct = 0; ct < 8; ++ct)
        qa[ct] = *(const f32x4*)(qA + (size_t)b * 128 + ct * 16 + g * 4);

    // prefetch tile 0 keys
    f32x4 kv[4][2];
    {
        const float* kp = kbase + (size_t)r15 * 128 + g * 8;
        #pragma unroll
        for (int kt = 0; kt < 4; ++kt) {
            kv[kt][0] = *(const f32x4*)(kp + kt * 32);
            kv[kt][1] = *(const f32x4*)(kp + kt * 32 + 4);
        }
    }

    ushort* dstb = z1b + (size_t)b * NT_PER_B * 2048;

    for (int t = 0; t < NT_PER_B; ++t) {
        // build A-side frags: k (kt 0..3), q*k (kt 4..7)
        bf16x8 afr[8];
        #pragma unroll
        for (int kt = 0; kt < 4; ++kt) {
            bf16x8 a, aq;
            #pragma unroll
            for (int h = 0; h < 2; ++h)
                #pragma unroll
                for (int j = 0; j < 4; ++j) {
                    float kf = kv[kt][h][j];
                    a[h * 4 + j]  = f2bf(kf);
                    aq[h * 4 + j] = f2bf(qv[kt][h][j] * kf);
                }
            afr[kt] = a;
            afr[4 + kt] = aq;
        }
        // prefetch next tile
        if (t < NT_PER_B - 1) {
            const int row = min((t + 1) * 16 + r15, L_SZ - 1);
            const float* kp = kbase + (size_t)row * 128 + g * 8;
            #pragma unroll
            for (int kt = 0; kt < 4; ++kt) {
                kv[kt][0] = *(const f32x4*)(kp + kt * 32);
                kv[kt][1] = *(const f32x4*)(kp + kt * 32 + 4);
            }
        }

        f32x4 acc[8];
        #pragma unroll
        for (int ct = 0; ct < 8; ++ct) {
            acc[ct] = (f32x4){0, 0, 0, 0};
            #pragma unroll
            for (int kt = 0; kt < 8; ++kt) {
                bf16x8 wf = *(const bf16x8*)(wlds + ((ct * 8 + kt) * 64 + lane) * 8);
                acc[ct] = __builtin_amdgcn_mfma_f32_16x16x32_bf16(wf, afr[kt], acc[ct], 0, 0, 0);
            }
        }

        // epilogue: lane = key-row r15; zero invalid rows; blob store
        const bool rvalid = (t < NT_PER_B - 1) | (r15 < 8);
        ushort* dst = dstb + (size_t)t * 2048;
        #pragma unroll
        for (int p = 0; p < 4; ++p) {
            bf16x8 o;
            #pragma unroll
            for (int jj = 0; jj < 8; ++jj) {
                const int ct = 2 * p + (jj >> 2), j = jj & 3;
                float v = acc[ct][j] + qa[ct][j];
                o[jj] = f2bf(rvalid ? v : 0.0f);
            }
            *(bf16x8*)(dst + p * 512 + lane * 8) = o;
        }
    }
}

// ---------------- S1: z1 stats from blob (sum/sumsq per channel) ----------------
__global__ void __launch_bounds__(256) s1_stats(const ushort* __restrict__ z1b,
                                                float* __restrict__ stats1)
{
    const int tid = threadIdx.x;
    const int gtid = blockIdx.x * 256 + tid;
    const int NTH = 512 * 256;                 // 131072
    const int CELLS = B_SZ * NT_PER_B * 256;   // 6815744 -> 52 iters
    const int lane = tid & 63, p = tid >> 6;
    const int r15 = lane & 15, g = lane >> 4;

    float ssum[8] = {0,0,0,0,0,0,0,0}, ssq[8] = {0,0,0,0,0,0,0,0};
    #pragma unroll 4
    for (int c = gtid; c < CELLS; c += NTH) {
        u16x8 v = *(const u16x8*)(z1b + (size_t)c * 8);
        #pragma unroll
        for (int jj = 0; jj < 8; ++jj) {
            float f = bf2f((short)v[jj]);
            ssum[jj] += f;
            ssq[jj] += f * f;
        }
    }
    #pragma unroll
    for (int jj = 0; jj < 8; ++jj) {
        float s = ssum[jj], q2 = ssq[jj];
        s += __shfl_xor(s, 1); s += __shfl_xor(s, 2); s += __shfl_xor(s, 4); s += __shfl_xor(s, 8);
        q2 += __shfl_xor(q2, 1); q2 += __shfl_xor(q2, 2); q2 += __shfl_xor(q2, 4); q2 += __shfl_xor(q2, 8);
        if (r15 == 0) {
            int ch = (2 * p + (jj >> 2)) * 16 + g * 4 + (jj & 3);
            atomicAdd(&stats1[ch], s);
            atomicAdd(&stats1[128 + ch], q2);
        }
    }
}

// ---------------- finalize: natural stats -> slot-order rstd / bias0 ----------------
__global__ void k_fin1p(const float* __restrict__ raw, float* __restrict__ fin1p)
{
    int c = threadIdx.x;   // 128
    float n = (float)NROWS;
    float m = raw[c] / n;
    float v = raw[128 + c] / n - m * m;
    float r = rsqrtf(v + 1e-8f);
    int kap = chan_to_slot(c);
    fin1p[kap] = r;
    fin1p[128 + kap] = -m * r;
}

__global__ void k_fin(const float* __restrict__ raw, float* __restrict__ fin, int nch)
{
    int c = threadIdx.x;
    if (c >= nch) return;
    float n = (float)NROWS;
    float m = raw[c] / n;
    float v = raw[nch + c] / n - m * m;
    float r = rsqrtf(v + 1e-8f);
    fin[c] = r;
    fin[nch + c] = -m * r;
}

// ---------------- K4: dice1(blob) -> z2^T = W2^T @ h^T -> z2 natural bf16 ----------------
// wave = one batch, 13 tiles. W2 frags from LDS; dice params from LDS (slot order).
__global__ void __launch_bounds__(256, 4) k4_z2(
    const ushort* __restrict__ z1b, const ushort* __restrict__ W2fT,
    const float* __restrict__ fin1p, const float* __restrict__ alpha1p,
    const float* __restrict__ b2, ushort* __restrict__ z2)
{
    __shared__ ushort w2s[4096];                   // 8 KB W2^T frag blob
    __shared__ float par[384];                     // rstd / bias0 / alpha (slot order)
    __shared__ __align__(16) ushort stg[4][640];   // per-wave 16 x 40 transpose tile

    const int tid = threadIdx.x, lane = tid & 63, wid = tid >> 6;
    const int b = blockIdx.x * 4 + wid;
    const int r15 = lane & 15, g = lane >> 4;

    for (int i = tid; i < 512; i += 256) ((u16x8*)w2s)[i] = ((const u16x8*)W2fT)[i];
    for (int i = tid; i < 384; i += 256) par[i] = (i < 256) ? fin1p[i] : alpha1p[i - 256];
    __syncthreads();

    f32x4 b2v[2];
    #pragma unroll
    for (int mt2 = 0; mt2 < 2; ++mt2)
        b2v[mt2] = *(const f32x4*)(b2 + mt2 * 16 + g * 4);

    const ushort* zb = z1b + (size_t)b * NT_PER_B * 2048;
    ushort* stgw = stg[wid];

    // prefetch tile 0
    bf16x8 zv[4];
    #pragma unroll
    for (int kt = 0; kt < 4; ++kt)
        zv[kt] = *(const bf16x8*)(zb + kt * 512 + lane * 8);

    for (int t = 0; t < NT_PER_B; ++t) {
        bf16x8 cur[4];
        #pragma unroll
        for (int kt = 0; kt < 4; ++kt) cur[kt] = zv[kt];
        if (t < NT_PER_B - 1) {
            const ushort* zp = zb + (size_t)(t + 1) * 2048 + lane * 8;
            #pragma unroll
            for (int kt = 0; kt < 4; ++kt)
                zv[kt] = *(const bf16x8*)(zp + kt * 512);
        }

        // dice1 -> h frags (B-operand ready, slot order)
        bf16x8 hv[4];
        #pragma unroll
        for (int kt = 0; kt < 4; ++kt) {
            const int base = kt * 32 + g * 8;
            f32x4 r0 = *(const f32x4*)(par + base);
            f32x4 r1 = *(const f32x4*)(par + base + 4);
            f32x4 o0 = *(const f32x4*)(par + 128 + base);
            f32x4 o1 = *(const f32x4*)(par + 128 + base + 4);
            f32x4 a0 = *(const f32x4*)(par + 256 + base);
            f32x4 a1 = *(const f32x4*)(par + 256 + base + 4);
            bf16x8 h;
            #pragma unroll
            for (int j = 0; j < 4; ++j) {
                float zl = bf2f(cur[kt][j]);
                float pg = sigm(zl * r0[j] + o0[j]);
                h[j] = f2bf(zl * (pg + (1.0f - pg) * a0[j]));
                float zh = bf2f(cur[kt][4 + j]);
                float ph = sigm(zh * r1[j] + o1[j]);
                h[4 + j] = f2bf(zh * (ph + (1.0f - ph) * a1[j]));
            }
            hv[kt] = h;
        }

        f32x4 acc[2];
        #pragma unroll
        for (int mt2 = 0; mt2 < 2; ++mt2) {
            acc[mt2] = (f32x4){0, 0, 0, 0};
            #pragma unroll
            for (int kt = 0; kt < 4; ++kt) {
                bf16x8 bf = *(const bf16x8*)(w2s + ((mt2 * 4 + kt) * 64 + lane) * 8);
                acc[mt2] = __builtin_amdgcn_mfma_f32_16x16x32_bf16(bf, hv[kt], acc[mt2], 0, 0, 0);
            }
        }

        // lane = row r15, channels mt2*16+g*4+j -> LDS transpose -> coalesced store
        #pragma unroll
        for (int mt2 = 0; mt2 < 2; ++mt2) {
            bf16x4 o;
            #pragma unroll
            for (int j = 0; j < 4; ++j)
                o[j] = f2bf(acc[mt2][j] + b2v[mt2][j]);
            *(bf16x4*)(stgw + r15 * 40 + mt2 * 16 + g * 4) = o;
        }
        u16x8 vv = *(const u16x8*)(stgw + (lane >> 2) * 40 + (lane & 3) * 8);
        *(u16x8*)(z2 + ((size_t)b * 208 + t * 16 + (lane >> 2)) * 32 + (lane & 3) * 8) = vv;
    }
}

// ---------------- S2: z2 stats (mask rows >= 200) ----------------
__global__ void __launch_bounds__(256) s2_stats(const ushort* __restrict__ z2,
                                                float* __restrict__ stats2)
{
    const int tid = threadIdx.x;
    const int gtid = blockIdx.x * 256 + tid;
    const int NTH = 256 * 256;                  // 65536
    const int CELLS = B_SZ * 208 * 4;           // 1703936 -> 26 iters
    const int lane = tid & 63, q = tid & 3;

    float ssum[8] = {0,0,0,0,0,0,0,0}, ssq[8] = {0,0,0,0,0,0,0,0};
    #pragma unroll 2
    for (int c = gtid; c < CELLS; c += NTH) {
        int rowq = c >> 2;
        int row208 = rowq - (rowq / 208) * 208;
        if (row208 < L_SZ) {
            u16x8 v = *(const u16x8*)(z2 + (size_t)c * 8);
            #pragma unroll
            for (int jj = 0; jj < 8; ++jj) {
                float f = bf2f((short)v[jj]);
                ssum[jj] += f;
                ssq[jj] += f * f;
            }
        }
    }
    #pragma unroll
    for (int jj = 0; jj < 8; ++jj) {
        float s = ssum[jj], q2 = ssq[jj];
        s += __shfl_xor(s, 4); s += __shfl_xor(s, 8); s += __shfl_xor(s, 16); s += __shfl_xor(s, 32);
        q2 += __shfl_xor(q2, 4); q2 += __shfl_xor(q2, 8); q2 += __shfl_xor(q2, 16); q2 += __shfl_xor(q2, 32);
        if (lane < 4) {
            int ch = q * 8 + jj;
            atomicAdd(&stats2[ch], s);
            atomicAdd(&stats2[32 + ch], q2);
        }
    }
}

// ---------------- K6: score = dice2(z2)@Wd + bd, mask, vectorized pooling ----------------
__global__ void __launch_bounds__(256) k6_score_pool(
    const ushort* __restrict__ z2, const float* __restrict__ keys,
    const int* __restrict__ keys_len, const float* __restrict__ fin2,
    const float* __restrict__ alpha2, const float* __restrict__ Wd,
    const float* __restrict__ bd, float* __restrict__ out)
{
    __shared__ float pp[129];
    __shared__ float sc[200];
    __shared__ f32x4 part6[8][32];
    int b = blockIdx.x, t = threadIdx.x;
    if (t < 64) pp[t] = fin2[t];
    else if (t < 96) pp[t] = alpha2[t - 64];
    else if (t < 128) pp[t] = Wd[t - 96];
    else if (t == 128) pp[128] = bd[0];
    __syncthreads();

    int klen = keys_len[b];
    if (t < 200) {
        float s = 0.0f;
        if (t < klen) {
            const ushort* zp = z2 + ((size_t)b * 208 + t) * 32;
            u16x8 zr[4];
            #pragma unroll
            for (int i = 0; i < 4; ++i) zr[i] = ((const u16x8*)zp)[i];
            s = pp[128];
            #pragma unroll
            for (int c = 0; c < 32; ++c) {
                float z = bf2f((short)zr[c >> 3][c & 7]);
                float zh = z * pp[c] + pp[32 + c];
                float pg = sigm(zh);
                float h = z * (pg + (1.0f - pg) * pp[64 + c]);
                s += h * pp[96 + c];
            }
        }
        sc[t] = s;
    }
    __syncthreads();

    const int c4 = t & 31, rg = t >> 5;      // 8 row-groups x 25 rows
    int lim = min(25, klen - rg * 25);       // may be <= 0
    f32x4 acc = (f32x4){0, 0, 0, 0};
    const float* kp = keys + ((size_t)b * 200 + rg * 25) * 128 + c4 * 4;
    for (int l = 0; l < lim; ++l) {
        float s = sc[rg * 25 + l];
        f32x4 kv = *(const f32x4*)(kp + (size_t)l * 128);
        acc.x += s * kv.x; acc.y += s * kv.y; acc.z += s * kv.z; acc.w += s * kv.w;
    }
    part6[rg][c4] = acc;
    __syncthreads();
    if (t < 32) {
        f32x4 r = (f32x4){0, 0, 0, 0};
        #pragma unroll
        for (int i = 0; i < 8; ++i) {
            f32x4 p = part6[i][t];
            r.x += p.x; r.y += p.y; r.z += p.z; r.w += p.w;
        }
        *(f32x4*)(out + (size_t)b * 128 + t * 4) = r;
    }
}

// ---------------- host launch ----------------
extern "C" void kernel_launch(void* const* d_in, const int* in_sizes, int n_in,
                              void* d_out, int out_size, void* d_ws, size_t ws_size,
                              hipStream_t stream) {
    const float* query    = (const float*)d_in[0];
    const float* keys     = (const float*)d_in[1];
    const int*   keys_len = (const int*)d_in[2];
    const float* W1       = (const float*)d_in[3];
    const float* b1       = (const float*)d_in[4];
    const float* alpha1   = (const float*)d_in[5];
    const float* W2       = (const float*)d_in[6];
    const float* b2       = (const float*)d_in[7];
    const float* alpha2   = (const float*)d_in[8];
    const float* Wd       = (const float*)d_in[9];
    const float* bd       = (const float*)d_in[10];
    float* out = (float*)d_out;

    char* ws = (char*)d_ws;
    ushort* z1b    = (ushort*)(ws);                          // 109,051,904 B
    ushort* z2     = (ushort*)(ws + 109051904);              // 27,262,976 B
    float*  qA     = (float*)(ws + 136314880);               // 1,048,576 B
    float*  Aprime = (float*)(ws + 137363456);               // 65,536 B
    ushort* Wf     = (ushort*)(ws + 137428992);              // 65,536 B
    ushort* W2fT   = (ushort*)(ws + 137494528);              // 8,192 B
    float*  alpha1p= (float*)(ws + 137502720);               // 512 B
    float*  stats  = (float*)(ws + 137503232);               // 2,048 B
    float*  fin1p  = (float*)(ws + 137505280);               // 1,024 B
    float*  fin2   = (float*)(ws + 137506304);               // 256 B

    k0_prep<<<128, 256, 0, stream>>>(W1, W2, alpha1, Aprime, Wf, W2fT, alpha1p, stats);
    k1_qA<<<B_SZ, 128, 0, stream>>>(query, Aprime, b1, qA);
    k2_main<<<512, 256, 0, stream>>>(query, keys, qA, Wf, z1b);
    s1_stats<<<512, 256, 0, stream>>>(z1b, stats);
    k_fin1p<<<1, 128, 0, stream>>>(stats, fin1p);
    k4_z2<<<512, 256, 0, stream>>>(z1b, W2fT, fin1p, alpha1p, b2, z2);
    s2_stats<<<256, 256, 0, stream>>>(z2, stats + 256);
    k_fin<<<1, 32, 0, stream>>>(stats + 256, fin2, 32);
    k6_score_pool<<<B_SZ, 256, 0, stream>>>(z2, keys, keys_len, fin2, alpha2, Wd, bd, out);
}

// Round 8
// 509.501 us; speedup vs baseline: 1.2730x; 1.2730x over previous
//
#include <hip/hip_runtime.h>
#include <hip/hip_bf16.h>
#include <stdint.h>

typedef __attribute__((ext_vector_type(8))) short bf16x8;
typedef __attribute__((ext_vector_type(4))) short bf16x4;
typedef __attribute__((ext_vector_type(8))) unsigned short u16x8;
typedef __attribute__((ext_vector_type(4))) float f32x4;

#define B_SZ 2048
#define L_SZ 200
#define NROWS (B_SZ * L_SZ)   // 409600 valid rows
#define NT 13                 // 16-row tiles per batch (last ragged)

__device__ __forceinline__ short f2bf(float f) {
    __bf16 h = (__bf16)f;
    return __builtin_bit_cast(short, h);
}
__device__ __forceinline__ float bf2f(short s) {
    union { uint32_t u; float f; } v; v.u = ((uint32_t)(uint16_t)s) << 16;
    return v.f;
}
__device__ __forceinline__ float sigm(float x) {
    return 1.0f / (1.0f + __expf(-x));
}

// ---------------- K0: weight prep + stat zeroing ----------------
// Aprime = W1a + W1c (f32 128x128 natural)
// Wf: bf16 A-frag blob of stacked [B'=W1b-W1c ; D=W1d] (256 k x 128 ch):
//   f = ((ct*8+kt)*64 + l)*8 + jj -> feat[k = kt*32+(l>>4)*8+jj][ch = ct*16+(l&15)]
// W2fT: bf16 A-frag blob of W2^T, natural channel order:
//   f = ((mt2*4+kt2)*64 + l)*8 + jj -> W2[kt2*32+(l>>4)*8+jj][mt2*16+(l&15)]
__global__ void k0_prep(const float* __restrict__ W1, const float* __restrict__ W2,
                        float* __restrict__ Aprime, ushort* __restrict__ Wf,
                        ushort* __restrict__ W2fT, float* __restrict__ stats)
{
    const int total = 16384 + 32768 + 4096 + 320;   // 53568
    for (int i = blockIdx.x * blockDim.x + threadIdx.x; i < total; i += gridDim.x * blockDim.x) {
        if (i < 16384) {
            int r = i >> 7, c = i & 127;
            Aprime[i] = W1[r * 128 + c] + W1[(256 + r) * 128 + c];
        } else if (i < 49152) {
            int f = i - 16384;
            int jj = f & 7, l = (f >> 3) & 63, kt = (f >> 9) & 7, ct = f >> 12;
            int kdim = kt * 32 + ((l >> 4) << 3) + jj;
            int ch = (ct << 4) + (l & 15);
            float v = (kdim < 128)
                ? (W1[(128 + kdim) * 128 + ch] - W1[(256 + kdim) * 128 + ch])
                : W1[(256 + kdim) * 128 + ch];   // == W1[384 + (kdim-128)][ch]
            Wf[f] = (ushort)f2bf(v);
        } else if (i < 49152 + 4096) {
            int f = i - 49152;
            int jj = f & 7, l = (f >> 3) & 63, kt2 = (f >> 9) & 3, mt2 = f >> 11;
            int ch = kt2 * 32 + ((l >> 4) << 3) + jj;
            int c2 = (mt2 << 4) + (l & 15);
            W2fT[f] = (ushort)f2bf(W2[ch * 32 + c2]);
        } else {
            stats[i - (49152 + 4096)] = 0.0f;   // 320 f32: stats1(256) + stats2(64)
        }
    }
}

// ---------------- K1: qA[b][c] = q[b]@A' + b1 ----------------
__global__ void k1_qA(const float* __restrict__ q, const float* __restrict__ Aprime,
                      const float* __restrict__ b1, float* __restrict__ qA)
{
    __shared__ float qs[128];
    int b = blockIdx.x, c = threadIdx.x;
    qs[c] = q[b * 128 + c];
    __syncthreads();
    float acc = b1[c];
    #pragma unroll 8
    for (int r = 0; r < 128; ++r) acc += qs[r] * Aprime[r * 128 + c];
    qA[b * 128 + c] = acc;
}

// ---------------- K2a: GEMM1 -> stats1 only (NO stores) ----------------
// block = batch (4 waves, wave cg covers 2 ct). Frags in registers (64 VGPR).
// mfma(wb, afr): D[ch_local][krow]: lane -> krow = lane&15, ch = ct*16 + g*4 + j.
__global__ void __launch_bounds__(256, 2) k2a_stats(
    const float* __restrict__ query, const float* __restrict__ keys,
    const float* __restrict__ qA, const ushort* __restrict__ Wf,
    float* __restrict__ stats1)
{
    const int tid = threadIdx.x, lane = tid & 63, cg = tid >> 6;
    const int b = blockIdx.x;
    const int r15 = lane & 15, g = lane >> 4;

    const float* kbase = keys + (size_t)b * L_SZ * 128;

    // prefetch tile 0 keys (issue before anything else)
    f32x4 kv[4][2];
    {
        const float* kp = kbase + (size_t)r15 * 128 + g * 8;
        #pragma unroll
        for (int kt = 0; kt < 4; ++kt) {
            kv[kt][0] = *(const f32x4*)(kp + kt * 32);
            kv[kt][1] = *(const f32x4*)(kp + kt * 32 + 4);
        }
    }

    // weight frags: 2 ct x 8 kt (64 VGPR)
    bf16x8 wb[2][8];
    #pragma unroll
    for (int ctl = 0; ctl < 2; ++ctl)
        #pragma unroll
        for (int kt = 0; kt < 8; ++kt)
            wb[ctl][kt] = *(const bf16x8*)(Wf + (((size_t)(cg * 2 + ctl) * 8 + kt) * 64 + lane) * 8);

    // q fragments
    f32x4 qv[4][2];
    #pragma unroll
    for (int kt = 0; kt < 4; ++kt) {
        const float* qp = query + (size_t)b * 128 + kt * 32 + g * 8;
        qv[kt][0] = *(const f32x4*)(qp);
        qv[kt][1] = *(const f32x4*)(qp + 4);
    }
    // qA for lane channels ch = (cg*2+ctl)*16 + g*4 + j
    f32x4 qa[2];
    #pragma unroll
    for (int ctl = 0; ctl < 2; ++ctl)
        qa[ctl] = *(const f32x4*)(qA + (size_t)b * 128 + (cg * 2 + ctl) * 16 + g * 4);

    float ssum[2][4] = {{0}}, ssq[2][4] = {{0}};

    for (int t = 0; t < NT; ++t) {
        bf16x8 afr[8];
        #pragma unroll
        for (int kt = 0; kt < 4; ++kt) {
            bf16x8 a, aq;
            #pragma unroll
            for (int h = 0; h < 2; ++h)
                #pragma unroll
                for (int j = 0; j < 4; ++j) {
                    float kf = kv[kt][h][j];
                    a[h * 4 + j]  = f2bf(kf);
                    aq[h * 4 + j] = f2bf(qv[kt][h][j] * kf);
                }
            afr[kt] = a;
            afr[4 + kt] = aq;
        }
        if (t < NT - 1) {
            const int row = min((t + 1) * 16 + r15, L_SZ - 1);
            const float* kp = kbase + (size_t)row * 128 + g * 8;
            #pragma unroll
            for (int kt = 0; kt < 4; ++kt) {
                kv[kt][0] = *(const f32x4*)(kp + kt * 32);
                kv[kt][1] = *(const f32x4*)(kp + kt * 32 + 4);
            }
        }

        f32x4 acc[2];
        #pragma unroll
        for (int ctl = 0; ctl < 2; ++ctl) {
            acc[ctl] = (f32x4){0, 0, 0, 0};
            #pragma unroll
            for (int kt = 0; kt < 8; ++kt)
                acc[ctl] = __builtin_amdgcn_mfma_f32_16x16x32_bf16(wb[ctl][kt], afr[kt], acc[ctl], 0, 0, 0);
        }

        const bool valid = (t < NT - 1) | (r15 < 8);
        if (valid) {
            #pragma unroll
            for (int ctl = 0; ctl < 2; ++ctl)
                #pragma unroll
                for (int j = 0; j < 4; ++j) {
                    float v = acc[ctl][j] + qa[ctl][j];
                    ssum[ctl][j] += v;
                    ssq[ctl][j] += v * v;
                }
        }
    }

    // reduce over krow (r15) within 16-lane groups
    #pragma unroll
    for (int ctl = 0; ctl < 2; ++ctl)
        #pragma unroll
        for (int j = 0; j < 4; ++j) {
            float s = ssum[ctl][j], q2 = ssq[ctl][j];
            s += __shfl_xor(s, 1); s += __shfl_xor(s, 2); s += __shfl_xor(s, 4); s += __shfl_xor(s, 8);
            q2 += __shfl_xor(q2, 1); q2 += __shfl_xor(q2, 2); q2 += __shfl_xor(q2, 4); q2 += __shfl_xor(q2, 8);
            if (r15 == 0) {
                int ch = (cg * 2 + ctl) * 16 + g * 4 + j;
                atomicAdd(&stats1[ch], s);
                atomicAdd(&stats1[128 + ch], q2);
            }
        }
}

// ---------------- k_fin: stats -> rstd, bias0 = -m*rstd (natural order) ----------------
__global__ void k_fin(const float* __restrict__ raw, float* __restrict__ fin, int nch)
{
    int c = threadIdx.x;
    if (c >= nch) return;
    float n = (float)NROWS;
    float m = raw[c] / n;
    float v = raw[nch + c] / n - m * m;
    float r = rsqrtf(v + 1e-8f);
    fin[c] = r;
    fin[nch + c] = -m * r;
}

// ---------------- K2b: recompute GEMM1 -> dice1 -> GEMM2 -> z2 + stats2 ----------------
// block = batch; 4 waves produce h (128 ch) into XOR-swizzled LDS tile;
// wave 0 consumes it for GEMM2 (8 MFMA), stores z2 natural, accumulates stats2.
__global__ void __launch_bounds__(256, 2) k2b_fused(
    const float* __restrict__ query, const float* __restrict__ keys,
    const float* __restrict__ qA, const ushort* __restrict__ Wf,
    const ushort* __restrict__ W2fT, const float* __restrict__ fin1,
    const float* __restrict__ alpha1, const float* __restrict__ b2,
    ushort* __restrict__ z2, float* __restrict__ stats2)
{
    __shared__ ushort hlds[16 * 136];              // h tile [krow][ch], pitch 136, XOR-swizzled
    __shared__ ushort w2s[4096];                   // W2^T frag blob (8 KB)
    __shared__ __align__(16) ushort zstg[16 * 40]; // wave-0 z2 transpose staging

    const int tid = threadIdx.x, lane = tid & 63, cg = tid >> 6;
    const int b = blockIdx.x;
    const int r15 = lane & 15, g = lane >> 4;

    const float* kbase = keys + (size_t)b * L_SZ * 128;

    // prefetch tile 0 keys
    f32x4 kv[4][2];
    {
        const float* kp = kbase + (size_t)r15 * 128 + g * 8;
        #pragma unroll
        for (int kt = 0; kt < 4; ++kt) {
            kv[kt][0] = *(const f32x4*)(kp + kt * 32);
            kv[kt][1] = *(const f32x4*)(kp + kt * 32 + 4);
        }
    }

    for (int i = tid; i < 512; i += 256) ((u16x8*)w2s)[i] = ((const u16x8*)W2fT)[i];

    // weight frags 2ct x 8kt
    bf16x8 wb[2][8];
    #pragma unroll
    for (int ctl = 0; ctl < 2; ++ctl)
        #pragma unroll
        for (int kt = 0; kt < 8; ++kt)
            wb[ctl][kt] = *(const bf16x8*)(Wf + (((size_t)(cg * 2 + ctl) * 8 + kt) * 64 + lane) * 8);

    f32x4 qv[4][2];
    #pragma unroll
    for (int kt = 0; kt < 4; ++kt) {
        const float* qp = query + (size_t)b * 128 + kt * 32 + g * 8;
        qv[kt][0] = *(const f32x4*)(qp);
        qv[kt][1] = *(const f32x4*)(qp + 4);
    }
    f32x4 qa[2];
    #pragma unroll
    for (int ctl = 0; ctl < 2; ++ctl)
        qa[ctl] = *(const f32x4*)(qA + (size_t)b * 128 + (cg * 2 + ctl) * 16 + g * 4);

    // dice params for this lane's 8 channels (loop-invariant)
    float prs[2][4], pof[2][4], pal[2][4];
    #pragma unroll
    for (int ctl = 0; ctl < 2; ++ctl)
        #pragma unroll
        for (int j = 0; j < 4; ++j) {
            int c = (cg * 2 + ctl) * 16 + g * 4 + j;
            prs[ctl][j] = fin1[c];
            pof[ctl][j] = fin1[128 + c];
            pal[ctl][j] = alpha1[c];
        }

    f32x4 b2v[2];
    #pragma unroll
    for (int mt2 = 0; mt2 < 2; ++mt2)
        b2v[mt2] = *(const f32x4*)(b2 + mt2 * 16 + g * 4);

    float s2sum[2][4] = {{0}}, s2sq[2][4] = {{0}};
    const int swz = (r15 & 7) << 4;   // byte XOR within row

    for (int t = 0; t < NT; ++t) {
        bf16x8 afr[8];
        #pragma unroll
        for (int kt = 0; kt < 4; ++kt) {
            bf16x8 a, aq;
            #pragma unroll
            for (int h = 0; h < 2; ++h)
                #pragma unroll
                for (int j = 0; j < 4; ++j) {
                    float kf = kv[kt][h][j];
                    a[h * 4 + j]  = f2bf(kf);
                    aq[h * 4 + j] = f2bf(qv[kt][h][j] * kf);
                }
            afr[kt] = a;
            afr[4 + kt] = aq;
        }
        if (t < NT - 1) {
            const int row = min((t + 1) * 16 + r15, L_SZ - 1);
            const float* kp = kbase + (size_t)row * 128 + g * 8;
            #pragma unroll
            for (int kt = 0; kt < 4; ++kt) {
                kv[kt][0] = *(const f32x4*)(kp + kt * 32);
                kv[kt][1] = *(const f32x4*)(kp + kt * 32 + 4);
            }
        }

        f32x4 acc[2];
        #pragma unroll
        for (int ctl = 0; ctl < 2; ++ctl) {
            acc[ctl] = (f32x4){0, 0, 0, 0};
            #pragma unroll
            for (int kt = 0; kt < 8; ++kt)
                acc[ctl] = __builtin_amdgcn_mfma_f32_16x16x32_bf16(wb[ctl][kt], afr[kt], acc[ctl], 0, 0, 0);
        }

        // dice1 -> h, write to swizzled LDS: hlds[krow=r15][ch]
        #pragma unroll
        for (int ctl = 0; ctl < 2; ++ctl) {
            bf16x4 hw;
            #pragma unroll
            for (int j = 0; j < 4; ++j) {
                float v = acc[ctl][j] + qa[ctl][j];
                float pg = sigm(v * prs[ctl][j] + pof[ctl][j]);
                hw[j] = f2bf(v * (pg + (1.0f - pg) * pal[ctl][j]));
            }
            const int colb = (cg * 2 + ctl) * 32 + g * 8;   // byte col = ch*2
            *(bf16x4*)((char*)hlds + r15 * 272 + (colb ^ swz)) = hw;
        }
        __syncthreads();

        if (cg == 0) {
            bf16x8 hf[4];
            #pragma unroll
            for (int kt2 = 0; kt2 < 4; ++kt2)
                hf[kt2] = *(const bf16x8*)((char*)hlds + r15 * 272 + ((kt2 * 64 + g * 16) ^ swz));

            f32x4 acc2[2];
            #pragma unroll
            for (int mt2 = 0; mt2 < 2; ++mt2) {
                acc2[mt2] = (f32x4){0, 0, 0, 0};
                #pragma unroll
                for (int kt2 = 0; kt2 < 4; ++kt2) {
                    bf16x8 wf2 = *(const bf16x8*)(w2s + ((mt2 * 4 + kt2) * 64 + lane) * 8);
                    acc2[mt2] = __builtin_amdgcn_mfma_f32_16x16x32_bf16(wf2, hf[kt2], acc2[mt2], 0, 0, 0);
                }
            }

            const bool valid = (t < NT - 1) | (r15 < 8);
            #pragma unroll
            for (int mt2 = 0; mt2 < 2; ++mt2) {
                bf16x4 o;
                #pragma unroll
                for (int j = 0; j < 4; ++j) {
                    float v = acc2[mt2][j] + b2v[mt2][j];
                    if (valid) { s2sum[mt2][j] += v; s2sq[mt2][j] += v * v; }
                    o[j] = f2bf(v);
                }
                *(bf16x4*)(zstg + r15 * 40 + mt2 * 16 + g * 4) = o;
            }
            u16x8 vv = *(const u16x8*)(zstg + (lane >> 2) * 40 + (lane & 3) * 8);
            *(u16x8*)(z2 + ((size_t)b * 208 + t * 16 + (lane >> 2)) * 32 + (lane & 3) * 8) = vv;
        }
        __syncthreads();
    }

    if (cg == 0) {
        #pragma unroll
        for (int mt2 = 0; mt2 < 2; ++mt2)
            #pragma unroll
            for (int j = 0; j < 4; ++j) {
                float s = s2sum[mt2][j], q2 = s2sq[mt2][j];
                s += __shfl_xor(s, 1); s += __shfl_xor(s, 2); s += __shfl_xor(s, 4); s += __shfl_xor(s, 8);
                q2 += __shfl_xor(q2, 1); q2 += __shfl_xor(q2, 2); q2 += __shfl_xor(q2, 4); q2 += __shfl_xor(q2, 8);
                if (r15 == 0) {
                    int c2 = mt2 * 16 + g * 4 + j;
                    atomicAdd(&stats2[c2], s);
                    atomicAdd(&stats2[32 + c2], q2);
                }
            }
    }
}

// ---------------- K6: score = dice2(z2)@Wd + bd, mask, vectorized pooling ----------------
__global__ void __launch_bounds__(256) k6_score_pool(
    const ushort* __restrict__ z2, const float* __restrict__ keys,
    const int* __restrict__ keys_len, const float* __restrict__ fin2,
    const float* __restrict__ alpha2, const float* __restrict__ Wd,
    const float* __restrict__ bd, float* __restrict__ out)
{
    __shared__ float pp[129];
    __shared__ float sc[200];
    __shared__ f32x4 part6[8][32];
    int b = blockIdx.x, t = threadIdx.x;
    if (t < 64) pp[t] = fin2[t];
    else if (t < 96) pp[t] = alpha2[t - 64];
    else if (t < 128) pp[t] = Wd[t - 96];
    else if (t == 128) pp[128] = bd[0];
    __syncthreads();

    int klen = keys_len[b];
    if (t < 200) {
        float s = 0.0f;
        if (t < klen) {
            const ushort* zp = z2 + ((size_t)b * 208 + t) * 32;
            u16x8 zr[4];
            #pragma unroll
            for (int i = 0; i < 4; ++i) zr[i] = ((const u16x8*)zp)[i];
            s = pp[128];
            #pragma unroll
            for (int c = 0; c < 32; ++c) {
                float z = bf2f((short)zr[c >> 3][c & 7]);
                float zh = z * pp[c] + pp[32 + c];
                float pg = sigm(zh);
                float h = z * (pg + (1.0f - pg) * pp[64 + c]);
                s += h * pp[96 + c];
            }
        }
        sc[t] = s;
    }
    __syncthreads();

    const int c4 = t & 31, rg = t >> 5;      // 8 row-groups x 25 rows
    int lim = min(25, klen - rg * 25);       // may be <= 0
    f32x4 acc = (f32x4){0, 0, 0, 0};
    const float* kp = keys + ((size_t)b * 200 + rg * 25) * 128 + c4 * 4;
    for (int l = 0; l < lim; ++l) {
        float s = sc[rg * 25 + l];
        f32x4 kv = *(const f32x4*)(kp + (size_t)l * 128);
        acc.x += s * kv.x; acc.y += s * kv.y; acc.z += s * kv.z; acc.w += s * kv.w;
    }
    part6[rg][c4] = acc;
    __syncthreads();
    if (t < 32) {
        f32x4 r = (f32x4){0, 0, 0, 0};
        #pragma unroll
        for (int i = 0; i < 8; ++i) {
            f32x4 p = part6[i][t];
            r.x += p.x; r.y += p.y; r.z += p.z; r.w += p.w;
        }
        *(f32x4*)(out + (size_t)b * 128 + t * 4) = r;
    }
}

// ---------------- host launch ----------------
extern "C" void kernel_launch(void* const* d_in, const int* in_sizes, int n_in,
                              void* d_out, int out_size, void* d_ws, size_t ws_size,
                              hipStream_t stream) {
    const float* query    = (const float*)d_in[0];
    const float* keys     = (const float*)d_in[1];
    const int*   keys_len = (const int*)d_in[2];
    const float* W1       = (const float*)d_in[3];
    const float* b1       = (const float*)d_in[4];
    const float* alpha1   = (const float*)d_in[5];
    const float* W2       = (const float*)d_in[6];
    const float* b2       = (const float*)d_in[7];
    const float* alpha2   = (const float*)d_in[8];
    const float* Wd       = (const float*)d_in[9];
    const float* bd       = (const float*)d_in[10];
    float* out = (float*)d_out;

    char* ws = (char*)d_ws;
    ushort* z2     = (ushort*)(ws);                          // 27,262,976 B (2048*208*32 bf16)
    float*  qA     = (float*)(ws + 27262976);                // 1,048,576 B
    float*  Aprime = (float*)(ws + 28311552);                // 65,536 B
    ushort* Wf     = (ushort*)(ws + 28377088);               // 65,536 B
    ushort* W2fT   = (ushort*)(ws + 28442624);               // 8,192 B
    float*  stats  = (float*)(ws + 28450816);                // 1,280 B (320 f32)
    float*  fin1   = (float*)(ws + 28452096);                // 1,024 B
    float*  fin2   = (float*)(ws + 28453120);                // 256 B

    k0_prep<<<64, 256, 0, stream>>>(W1, W2, Aprime, Wf, W2fT, stats);
    k1_qA<<<B_SZ, 128, 0, stream>>>(query, Aprime, b1, qA);
    k2a_stats<<<B_SZ, 256, 0, stream>>>(query, keys, qA, Wf, stats);
    k_fin<<<1, 128, 0, stream>>>(stats, fin1, 128);
    k2b_fused<<<B_SZ, 256, 0, stream>>>(query, keys, qA, Wf, W2fT, fin1, alpha1, b2, z2, stats + 256);
    k_fin<<<1, 32, 0, stream>>>(stats + 256, fin2, 32);
    k6_score_pool<<<B_SZ, 256, 0, stream>>>(z2, keys, keys_len, fin2, alpha2, Wd, bd, out);
}

// Round 9
// 498.972 us; speedup vs baseline: 1.2999x; 1.0211x over previous
//
#include <hip/hip_runtime.h>
#include <hip/hip_bf16.h>
#include <stdint.h>

typedef __attribute__((ext_vector_type(8))) short bf16x8;
typedef __attribute__((ext_vector_type(4))) short bf16x4;
typedef __attribute__((ext_vector_type(8))) unsigned short u16x8;
typedef __attribute__((ext_vector_type(4))) float f32x4;

#define B_SZ 2048
#define L_SZ 200
#define NROWS (B_SZ * L_SZ)   // 409600 valid rows
#define NT 13                 // 16-row tiles per batch (last ragged)

__device__ __forceinline__ short f2bf(float f) {
    __bf16 h = (__bf16)f;
    return __builtin_bit_cast(short, h);
}
__device__ __forceinline__ float bf2f(short s) {
    union { uint32_t u; float f; } v; v.u = ((uint32_t)(uint16_t)s) << 16;
    return v.f;
}
__device__ __forceinline__ float sigm(float x) {
    return 1.0f / (1.0f + __expf(-x));
}

// Stage one 16-row keys tile (8 KB) into wave-private LDS via global_load_lds.
// LDS layout: [rslot 0..15][phys granule 0..31], phys = logical ^ (rslot&7).
// Source address is per-lane pre-swizzled (dense within each 512B row).
__device__ __forceinline__ void stage_tile(const float* kbase, int t, void* ldsbase, int lane)
{
    const int l5 = lane >> 5, p = lane & 31;
    #pragma unroll
    for (int i = 0; i < 8; ++i) {
        const int rslot = 2 * i + l5;
        const int grow = min(t * 16 + rslot, L_SZ - 1);
        const char* src = (const char*)kbase + (size_t)grow * 512
                        + (size_t)((p ^ (rslot & 7)) << 4);
        __builtin_amdgcn_global_load_lds(
            (const __attribute__((address_space(1))) uint32_t*)src,
            (__attribute__((address_space(3))) uint32_t*)((char*)ldsbase + i * 1024),
            16, 0, 0);
    }
}

// ---------------- K0: weight prep + stat zeroing ----------------
__global__ void k0_prep(const float* __restrict__ W1, const float* __restrict__ W2,
                        float* __restrict__ Aprime, ushort* __restrict__ Wf,
                        ushort* __restrict__ W2fT, float* __restrict__ stats)
{
    const int total = 16384 + 32768 + 4096 + 320;
    for (int i = blockIdx.x * blockDim.x + threadIdx.x; i < total; i += gridDim.x * blockDim.x) {
        if (i < 16384) {
            int r = i >> 7, c = i & 127;
            Aprime[i] = W1[r * 128 + c] + W1[(256 + r) * 128 + c];
        } else if (i < 49152) {
            int f = i - 16384;
            int jj = f & 7, l = (f >> 3) & 63, kt = (f >> 9) & 7, ct = f >> 12;
            int kdim = kt * 32 + ((l >> 4) << 3) + jj;
            int ch = (ct << 4) + (l & 15);
            float v = (kdim < 128)
                ? (W1[(128 + kdim) * 128 + ch] - W1[(256 + kdim) * 128 + ch])
                : W1[(256 + kdim) * 128 + ch];
            Wf[f] = (ushort)f2bf(v);
        } else if (i < 49152 + 4096) {
            int f = i - 49152;
            int jj = f & 7, l = (f >> 3) & 63, kt2 = (f >> 9) & 3, mt2 = f >> 11;
            int ch = kt2 * 32 + ((l >> 4) << 3) + jj;
            int c2 = (mt2 << 4) + (l & 15);
            W2fT[f] = (ushort)f2bf(W2[ch * 32 + c2]);
        } else {
            stats[i - (49152 + 4096)] = 0.0f;
        }
    }
}

// ---------------- K1: qA[b][c] = q[b]@A' + b1 ----------------
__global__ void k1_qA(const float* __restrict__ q, const float* __restrict__ Aprime,
                      const float* __restrict__ b1, float* __restrict__ qA)
{
    __shared__ float qs[128];
    int b = blockIdx.x, c = threadIdx.x;
    qs[c] = q[b * 128 + c];
    __syncthreads();
    float acc = b1[c];
    #pragma unroll 8
    for (int r = 0; r < 128; ++r) acc += qs[r] * Aprime[r * 128 + c];
    qA[b * 128 + c] = acc;
}

// ---------------- K2a: GEMM1 -> stats1, dense LDS-staged keys, no stores ----------------
__global__ void __launch_bounds__(256, 2) k2a_stats(
    const float* __restrict__ query, const float* __restrict__ keys,
    const float* __restrict__ qA, const ushort* __restrict__ Wf,
    float* __restrict__ stats1)
{
    __shared__ __align__(16) char klds[4][2][8192];
    const int tid = threadIdx.x, lane = tid & 63, cg = tid >> 6;
    const int b = blockIdx.x;
    const int r15 = lane & 15, g = lane >> 4;
    const float* kbase = keys + (size_t)b * L_SZ * 128;

    stage_tile(kbase, 0, &klds[cg][0][0], lane);   // tile 0 -> buf 0 (issue first)

    // weight frags in registers (64 VGPR): 2 ct x 8 kt
    bf16x8 wb[2][8];
    #pragma unroll
    for (int ctl = 0; ctl < 2; ++ctl)
        #pragma unroll
        for (int kt = 0; kt < 8; ++kt)
            wb[ctl][kt] = *(const bf16x8*)(Wf + (((size_t)(cg * 2 + ctl) * 8 + kt) * 64 + lane) * 8);

    f32x4 qv[4][2];
    #pragma unroll
    for (int kt = 0; kt < 4; ++kt) {
        const float* qp = query + (size_t)b * 128 + kt * 32 + g * 8;
        qv[kt][0] = *(const f32x4*)(qp);
        qv[kt][1] = *(const f32x4*)(qp + 4);
    }
    f32x4 qa[2];
    #pragma unroll
    for (int ctl = 0; ctl < 2; ++ctl)
        qa[ctl] = *(const f32x4*)(qA + (size_t)b * 128 + (cg * 2 + ctl) * 16 + g * 4);

    float ssum[2][4] = {{0}}, ssq[2][4] = {{0}};
    const int rsw = r15 & 7;
    int buf = 0;

    for (int t = 0; t < NT; ++t) {
        if (t < NT - 1) {
            stage_tile(kbase, t + 1, &klds[cg][buf ^ 1][0], lane);
            asm volatile("s_waitcnt vmcnt(8)" ::: "memory");   // current buf ready, 8 in flight
        } else {
            asm volatile("s_waitcnt vmcnt(0)" ::: "memory");
        }
        __builtin_amdgcn_sched_barrier(0);

        const char* rb = &klds[cg][buf][0];
        bf16x8 afr[8];
        #pragma unroll
        for (int kt = 0; kt < 4; ++kt) {
            f32x4 k0 = *(const f32x4*)(rb + r15 * 512 + (((kt * 8 + g * 2 + 0) ^ rsw) << 4));
            f32x4 k1 = *(const f32x4*)(rb + r15 * 512 + (((kt * 8 + g * 2 + 1) ^ rsw) << 4));
            bf16x8 a, aq;
            #pragma unroll
            for (int j = 0; j < 4; ++j) {
                a[j] = f2bf(k0[j]);  a[4 + j] = f2bf(k1[j]);
                aq[j] = f2bf(qv[kt][0][j] * k0[j]);
                aq[4 + j] = f2bf(qv[kt][1][j] * k1[j]);
            }
            afr[kt] = a;
            afr[4 + kt] = aq;
        }

        f32x4 acc[2];
        #pragma unroll
        for (int ctl = 0; ctl < 2; ++ctl) {
            acc[ctl] = (f32x4){0, 0, 0, 0};
            #pragma unroll
            for (int kt = 0; kt < 8; ++kt)
                acc[ctl] = __builtin_amdgcn_mfma_f32_16x16x32_bf16(wb[ctl][kt], afr[kt], acc[ctl], 0, 0, 0);
        }

        const bool valid = (t < NT - 1) | (r15 < 8);
        if (valid) {
            #pragma unroll
            for (int ctl = 0; ctl < 2; ++ctl)
                #pragma unroll
                for (int j = 0; j < 4; ++j) {
                    float v = acc[ctl][j] + qa[ctl][j];
                    ssum[ctl][j] += v;
                    ssq[ctl][j] += v * v;
                }
        }
        buf ^= 1;
    }

    #pragma unroll
    for (int ctl = 0; ctl < 2; ++ctl)
        #pragma unroll
        for (int j = 0; j < 4; ++j) {
            float s = ssum[ctl][j], q2 = ssq[ctl][j];
            s += __shfl_xor(s, 1); s += __shfl_xor(s, 2); s += __shfl_xor(s, 4); s += __shfl_xor(s, 8);
            q2 += __shfl_xor(q2, 1); q2 += __shfl_xor(q2, 2); q2 += __shfl_xor(q2, 4); q2 += __shfl_xor(q2, 8);
            if (r15 == 0) {
                int ch = (cg * 2 + ctl) * 16 + g * 4 + j;
                atomicAdd(&stats1[ch], s);
                atomicAdd(&stats1[128 + ch], q2);
            }
        }
}

// ---------------- k_fin: stats -> rstd, bias0 = -m*rstd ----------------
__global__ void k_fin(const float* __restrict__ raw, float* __restrict__ fin, int nch)
{
    int c = threadIdx.x;
    if (c >= nch) return;
    float n = (float)NROWS;
    float m = raw[c] / n;
    float v = raw[nch + c] / n - m * m;
    float r = rsqrtf(v + 1e-8f);
    fin[c] = r;
    fin[nch + c] = -m * r;
}

// ---------------- K2b: recompute GEMM1 -> dice1 -> GEMM2 -> z2 + stats2 ----------------
__global__ void __launch_bounds__(256, 2) k2b_fused(
    const float* __restrict__ query, const float* __restrict__ keys,
    const float* __restrict__ qA, const ushort* __restrict__ Wf,
    const ushort* __restrict__ W2fT, const float* __restrict__ fin1,
    const float* __restrict__ alpha1, const float* __restrict__ b2,
    ushort* __restrict__ z2, float* __restrict__ stats2)
{
    __shared__ __align__(16) char klds[4][2][8192];
    __shared__ ushort hlds[16 * 136];
    __shared__ ushort w2s[4096];
    __shared__ __align__(16) ushort zstg[16 * 40];

    const int tid = threadIdx.x, lane = tid & 63, cg = tid >> 6;
    const int b = blockIdx.x;
    const int r15 = lane & 15, g = lane >> 4;
    const float* kbase = keys + (size_t)b * L_SZ * 128;

    stage_tile(kbase, 0, &klds[cg][0][0], lane);

    for (int i = tid; i < 512; i += 256) ((u16x8*)w2s)[i] = ((const u16x8*)W2fT)[i];

    bf16x8 wb[2][8];
    #pragma unroll
    for (int ctl = 0; ctl < 2; ++ctl)
        #pragma unroll
        for (int kt = 0; kt < 8; ++kt)
            wb[ctl][kt] = *(const bf16x8*)(Wf + (((size_t)(cg * 2 + ctl) * 8 + kt) * 64 + lane) * 8);

    f32x4 qv[4][2];
    #pragma unroll
    for (int kt = 0; kt < 4; ++kt) {
        const float* qp = query + (size_t)b * 128 + kt * 32 + g * 8;
        qv[kt][0] = *(const f32x4*)(qp);
        qv[kt][1] = *(const f32x4*)(qp + 4);
    }
    f32x4 qa[2];
    #pragma unroll
    for (int ctl = 0; ctl < 2; ++ctl)
        qa[ctl] = *(const f32x4*)(qA + (size_t)b * 128 + (cg * 2 + ctl) * 16 + g * 4);

    float prs[2][4], pof[2][4], pal[2][4];
    #pragma unroll
    for (int ctl = 0; ctl < 2; ++ctl)
        #pragma unroll
        for (int j = 0; j < 4; ++j) {
            int c = (cg * 2 + ctl) * 16 + g * 4 + j;
            prs[ctl][j] = fin1[c];
            pof[ctl][j] = fin1[128 + c];
            pal[ctl][j] = alpha1[c];
        }

    f32x4 b2v[2];
    #pragma unroll
    for (int mt2 = 0; mt2 < 2; ++mt2)
        b2v[mt2] = *(const f32x4*)(b2 + mt2 * 16 + g * 4);

    float s2sum[2][4] = {{0}}, s2sq[2][4] = {{0}};
    const int rsw = r15 & 7;
    const int swz = (r15 & 7) << 4;
    int buf = 0;

    for (int t = 0; t < NT; ++t) {
        if (t < NT - 1) stage_tile(kbase, t + 1, &klds[cg][buf ^ 1][0], lane);
        asm volatile("s_waitcnt vmcnt(8)" ::: "memory");
        __builtin_amdgcn_sched_barrier(0);

        const char* rb = &klds[cg][buf][0];
        bf16x8 afr[8];
        #pragma unroll
        for (int kt = 0; kt < 4; ++kt) {
            f32x4 k0 = *(const f32x4*)(rb + r15 * 512 + (((kt * 8 + g * 2 + 0) ^ rsw) << 4));
            f32x4 k1 = *(const f32x4*)(rb + r15 * 512 + (((kt * 8 + g * 2 + 1) ^ rsw) << 4));
            bf16x8 a, aq;
            #pragma unroll
            for (int j = 0; j < 4; ++j) {
                a[j] = f2bf(k0[j]);  a[4 + j] = f2bf(k1[j]);
                aq[j] = f2bf(qv[kt][0][j] * k0[j]);
                aq[4 + j] = f2bf(qv[kt][1][j] * k1[j]);
            }
            afr[kt] = a;
            afr[4 + kt] = aq;
        }

        f32x4 acc[2];
        #pragma unroll
        for (int ctl = 0; ctl < 2; ++ctl) {
            acc[ctl] = (f32x4){0, 0, 0, 0};
            #pragma unroll
            for (int kt = 0; kt < 8; ++kt)
                acc[ctl] = __builtin_amdgcn_mfma_f32_16x16x32_bf16(wb[ctl][kt], afr[kt], acc[ctl], 0, 0, 0);
        }

        // dice1 -> h -> swizzled hlds
        #pragma unroll
        for (int ctl = 0; ctl < 2; ++ctl) {
            bf16x4 hw;
            #pragma unroll
            for (int j = 0; j < 4; ++j) {
                float v = acc[ctl][j] + qa[ctl][j];
                float pg = sigm(v * prs[ctl][j] + pof[ctl][j]);
                hw[j] = f2bf(v * (pg + (1.0f - pg) * pal[ctl][j]));
            }
            const int colb = (cg * 2 + ctl) * 32 + g * 8;
            *(bf16x4*)((char*)hlds + r15 * 272 + (colb ^ swz)) = hw;
        }
        __syncthreads();

        if (cg == 0) {
            bf16x8 hf[4];
            #pragma unroll
            for (int kt2 = 0; kt2 < 4; ++kt2)
                hf[kt2] = *(const bf16x8*)((char*)hlds + r15 * 272 + ((kt2 * 64 + g * 16) ^ swz));

            f32x4 acc2[2];
            #pragma unroll
            for (int mt2 = 0; mt2 < 2; ++mt2) {
                acc2[mt2] = (f32x4){0, 0, 0, 0};
                #pragma unroll
                for (int kt2 = 0; kt2 < 4; ++kt2) {
                    bf16x8 wf2 = *(const bf16x8*)(w2s + ((mt2 * 4 + kt2) * 64 + lane) * 8);
                    acc2[mt2] = __builtin_amdgcn_mfma_f32_16x16x32_bf16(wf2, hf[kt2], acc2[mt2], 0, 0, 0);
                }
            }

            const bool valid = (t < NT - 1) | (r15 < 8);
            #pragma unroll
            for (int mt2 = 0; mt2 < 2; ++mt2) {
                bf16x4 o;
                #pragma unroll
                for (int j = 0; j < 4; ++j) {
                    float v = acc2[mt2][j] + b2v[mt2][j];
                    if (valid) { s2sum[mt2][j] += v; s2sq[mt2][j] += v * v; }
                    o[j] = f2bf(v);
                }
                *(bf16x4*)(zstg + r15 * 40 + mt2 * 16 + g * 4) = o;
            }
            u16x8 vv = *(const u16x8*)(zstg + (lane >> 2) * 40 + (lane & 3) * 8);
            *(u16x8*)(z2 + ((size_t)b * 208 + t * 16 + (lane >> 2)) * 32 + (lane & 3) * 8) = vv;
        }
        __syncthreads();
        buf ^= 1;
    }

    if (cg == 0) {
        #pragma unroll
        for (int mt2 = 0; mt2 < 2; ++mt2)
            #pragma unroll
            for (int j = 0; j < 4; ++j) {
                float s = s2sum[mt2][j], q2 = s2sq[mt2][j];
                s += __shfl_xor(s, 1); s += __shfl_xor(s, 2); s += __shfl_xor(s, 4); s += __shfl_xor(s, 8);
                q2 += __shfl_xor(q2, 1); q2 += __shfl_xor(q2, 2); q2 += __shfl_xor(q2, 4); q2 += __shfl_xor(q2, 8);
                if (r15 == 0) {
                    int c2 = mt2 * 16 + g * 4 + j;
                    atomicAdd(&stats2[c2], s);
                    atomicAdd(&stats2[32 + c2], q2);
                }
            }
    }
}

// ---------------- K6: score = dice2(z2)@Wd + bd, mask, vectorized pooling ----------------
__global__ void __launch_bounds__(256) k6_score_pool(
    const ushort* __restrict__ z2, const float* __restrict__ keys,
    const int* __restrict__ keys_len, const float* __restrict__ fin2,
    const float* __restrict__ alpha2, const float* __restrict__ Wd,
    const float* __restrict__ bd, float* __restrict__ out)
{
    __shared__ float pp[129];
    __shared__ float sc[200];
    __shared__ f32x4 part6[8][32];
    int b = blockIdx.x, t = threadIdx.x;
    if (t < 64) pp[t] = fin2[t];
    else if (t < 96) pp[t] = alpha2[t - 64];
    else if (t < 128) pp[t] = Wd[t - 96];
    else if (t == 128) pp[128] = bd[0];
    __syncthreads();

    int klen = keys_len[b];
    if (t < 200) {
        float s = 0.0f;
        if (t < klen) {
            const ushort* zp = z2 + ((size_t)b * 208 + t) * 32;
            u16x8 zr[4];
            #pragma unroll
            for (int i = 0; i < 4; ++i) zr[i] = ((const u16x8*)zp)[i];
            s = pp[128];
            #pragma unroll
            for (int c = 0; c < 32; ++c) {
                float z = bf2f((short)zr[c >> 3][c & 7]);
                float zh = z * pp[c] + pp[32 + c];
                float pg = sigm(zh);
                float h = z * (pg + (1.0f - pg) * pp[64 + c]);
                s += h * pp[96 + c];
            }
        }
        sc[t] = s;
    }
    __syncthreads();

    const int c4 = t & 31, rg = t >> 5;
    int lim = min(25, klen - rg * 25);
    f32x4 acc = (f32x4){0, 0, 0, 0};
    const float* kp = keys + ((size_t)b * 200 + rg * 25) * 128 + c4 * 4;
    for (int l = 0; l < lim; ++l) {
        float s = sc[rg * 25 + l];
        f32x4 kv = *(const f32x4*)(kp + (size_t)l * 128);
        acc.x += s * kv.x; acc.y += s * kv.y; acc.z += s * kv.z; acc.w += s * kv.w;
    }
    part6[rg][c4] = acc;
    __syncthreads();
    if (t < 32) {
        f32x4 r = (f32x4){0, 0, 0, 0};
        #pragma unroll
        for (int i = 0; i < 8; ++i) {
            f32x4 p = part6[i][t];
            r.x += p.x; r.y += p.y; r.z += p.z; r.w += p.w;
        }
        *(f32x4*)(out + (size_t)b * 128 + t * 4) = r;
    }
}

// ---------------- host launch ----------------
extern "C" void kernel_launch(void* const* d_in, const int* in_sizes, int n_in,
                              void* d_out, int out_size, void* d_ws, size_t ws_size,
                              hipStream_t stream) {
    const float* query    = (const float*)d_in[0];
    const float* keys     = (const float*)d_in[1];
    const int*   keys_len = (const int*)d_in[2];
    const float* W1       = (const float*)d_in[3];
    const float* b1       = (const float*)d_in[4];
    const float* alpha1   = (const float*)d_in[5];
    const float* W2       = (const float*)d_in[6];
    const float* b2       = (const float*)d_in[7];
    const float* alpha2   = (const float*)d_in[8];
    const float* Wd       = (const float*)d_in[9];
    const float* bd       = (const float*)d_in[10];
    float* out = (float*)d_out;

    char* ws = (char*)d_ws;
    ushort* z2     = (ushort*)(ws);                          // 27,262,976 B
    float*  qA     = (float*)(ws + 27262976);                // 1,048,576 B
    float*  Aprime = (float*)(ws + 28311552);                // 65,536 B
    ushort* Wf     = (ushort*)(ws + 28377088);               // 65,536 B
    ushort* W2fT   = (ushort*)(ws + 28442624);               // 8,192 B
    float*  stats  = (float*)(ws + 28450816);                // 1,280 B
    float*  fin1   = (float*)(ws + 28452096);                // 1,024 B
    float*  fin2   = (float*)(ws + 28453120);                // 256 B

    k0_prep<<<64, 256, 0, stream>>>(W1, W2, Aprime, Wf, W2fT, stats);
    k1_qA<<<B_SZ, 128, 0, stream>>>(query, Aprime, b1, qA);
    k2a_stats<<<B_SZ, 256, 0, stream>>>(query, keys, qA, Wf, stats);
    k_fin<<<1, 128, 0, stream>>>(stats, fin1, 128);
    k2b_fused<<<B_SZ, 256, 0, stream>>>(query, keys, qA, Wf, W2fT, fin1, alpha1, b2, z2, stats + 256);
    k_fin<<<1, 32, 0, stream>>>(stats + 256, fin2, 32);
    k6_score_pool<<<B_SZ, 256, 0, stream>>>(z2, keys, keys_len, fin2, alpha2, Wd, bd, out);
}